// Round 17
// baseline (151.772 us; speedup 1.0000x reference)
//
#include <hip/hip_runtime.h>
#include <math.h>

#define T_DIM 1024
#define B_DIM 16
#define C_DIM 1024
#define H_DIM 16
#define K_TAPS 7
#define PAD_LEFT 3
#define OUT_DIM 1024
#define M_DIM (T_DIM * B_DIM)   // 16384
#define HK 112
#define HKP 128
#define KD 1024

typedef __attribute__((ext_vector_type(8))) short bf16x8;
typedef __attribute__((ext_vector_type(4))) float f32x4;

__device__ __forceinline__ ushort f2bf(float f) {
    union { float f; unsigned u; } v; v.f = f;
    unsigned u = v.u;
    u += 0x7fffu + ((u >> 16) & 1u);
    return (ushort)(u >> 16);
}
__device__ __forceinline__ float bf2f(ushort h) {
    union { unsigned u; float f; } v; v.u = ((unsigned)h) << 16;
    return v.f;
}

// ---------------------------------------------------------------------------
// Fused prep: blocks 0-8191 convert x -> bf16; blocks 8192+ transpose weights.
// ---------------------------------------------------------------------------
__global__ __launch_bounds__(256) void prep(const float* __restrict__ x,
                                            ushort* __restrict__ xb,
                                            const float* __restrict__ W1s,
                                            const float* __restrict__ Wqs,
                                            const float* __restrict__ W2s,
                                            ushort* __restrict__ W1t,
                                            ushort* __restrict__ Wqt,
                                            ushort* __restrict__ W2t) {
    __shared__ float tile[32][33];
    const int bx = blockIdx.x;
    if (bx < 8192) {
        int i = bx * 256 + threadIdx.x;
        const float4* p = (const float4*)x;
        float4 a = p[2 * i], b = p[2 * i + 1];
        uint4 o;
        o.x = (unsigned)f2bf(a.x) | ((unsigned)f2bf(a.y) << 16);
        o.y = (unsigned)f2bf(a.z) | ((unsigned)f2bf(a.w) << 16);
        o.z = (unsigned)f2bf(b.x) | ((unsigned)f2bf(b.y) << 16);
        o.w = (unsigned)f2bf(b.z) | ((unsigned)f2bf(b.w) << 16);
        ((uint4*)xb)[i] = o;
        return;
    }
    int tb  = bx - 8192;
    int nbx = tb % 68;
    int k0  = (tb / 68) * 32;
    const float* W; ushort* Wt; int N, Npad, nb;
    if (nbx < 32)      { W = W1s; Wt = W1t; N = 1024; Npad = 1024; nb = nbx; }
    else if (nbx < 36) { W = Wqs; Wt = Wqt; N = 112;  Npad = 128;  nb = nbx - 32; }
    else               { W = W2s; Wt = W2t; N = 1024; Npad = 1024; nb = nbx - 36; }
    int n0 = nb * 32;
    int tx = threadIdx.x & 31, ty = threadIdx.x >> 5;
#pragma unroll
    for (int j = 0; j < 4; ++j) {
        int k = k0 + ty * 4 + j;
        int n = n0 + tx;
        tile[ty * 4 + j][tx] = (n < N) ? W[(size_t)k * N + n] : 0.f;
    }
    __syncthreads();
#pragma unroll
    for (int j = 0; j < 4; ++j) {
        int n = n0 + ty * 4 + j;
        if (n < Npad)
            Wt[(size_t)n * KD + k0 + tx] = f2bf(tile[tx][ty * 4 + j]);
    }
}

// ---------------------------------------------------------------------------
// Overlapped-pipeline GEMM: BM=256, BN=128, BK=32/slot, 512 thr (8 waves
// 4Mx2N, 64x64 out/wave -> acc only 64 regs), 4 LDS slots/matrix (96 KiB).
// Register double-buffer: frags(p+1) are ds_read DURING MFMA(p) (no
// dependence -> LDS pipe and matrix pipe overlap). ONE barrier per phase.
// Safety ledger (induction-checked):
//  - stage at phase p targets slot (p+3)&3, whose reads (frags at that slot)
//    were drained by each wave's lgkm0 >=2 barriers earlier.
//  - reads at p read slot (p+1)&3 staged at p-2; vmcnt(3) at end of p-1
//    drains it (3 loads/stage, 2 stage-groups outstanding).
//  - tail: p=28 vmcnt(3); p=29 vmcnt(0); p>=30 no stage -> no vmcnt/barrier.
// Swizzle identical to the verified 0-conflict pattern: 16B slot' =
// slot^((row>>1)&3), pre-swizzled global source + swizzled read base.
// ---------------------------------------------------------------------------
#define READF(FA, FB, SLOT)                                                   \
    _Pragma("unroll")                                                         \
    for (int m = 0; m < 4; ++m)                                               \
        FA[m] = *(const bf16x8*)(Ab + (SLOT)*8192 + aOff + m*512);            \
    _Pragma("unroll")                                                         \
    for (int n = 0; n < 4; ++n)                                               \
        FB[n] = *(const bf16x8*)(Bb + (SLOT)*4096 + bOff + n*512);

#define MFMAB(FA, FB)                                                         \
    __builtin_amdgcn_s_setprio(1);                                            \
    _Pragma("unroll")                                                         \
    for (int m = 0; m < 4; ++m)                                               \
        _Pragma("unroll")                                                     \
        for (int n = 0; n < 4; ++n)                                           \
            acc[m][n] = __builtin_amdgcn_mfma_f32_16x16x32_bf16(              \
                FA[m], FB[n], acc[m][n], 0, 0, 0);                            \
    __builtin_amdgcn_s_setprio(0);

#define VM3 asm volatile("s_waitcnt vmcnt(3)" ::: "memory")
#define VM0 asm volatile("s_waitcnt vmcnt(0)" ::: "memory")

#define OLPHASE(CA, CB, NA, NB, RSLOT, DO_STAGE, SSLOT, SKSUB, VMS)           \
    {                                                                         \
        if (DO_STAGE) stage(SSLOT, SKSUB);                                    \
        READF(NA, NB, RSLOT)                                                  \
        __builtin_amdgcn_sched_barrier(0);                                    \
        MFMAB(CA, CB)                                                         \
        asm volatile("s_waitcnt lgkmcnt(0)" ::: "memory");                    \
        VMS;                                                                  \
        __builtin_amdgcn_sched_barrier(0);                                    \
        __builtin_amdgcn_s_barrier();                                         \
        __builtin_amdgcn_sched_barrier(0);                                    \
    }

template <bool OUT_BF16>
__global__ __launch_bounds__(512, 1) void gemm_ol(
    const ushort* __restrict__ A, const ushort* __restrict__ Bt,
    const float* __restrict__ bias, void* __restrict__ Cp, int ldc) {
    __shared__ ushort Lds[4 * 8192 + 4 * 4096];   // A slots 0-3, B slots 0-3

    const int tid  = threadIdx.x;
    const int lane = tid & 63;
    const int wid  = tid >> 6;
    const int wr = wid >> 1;        // 0..3  (M quarter, 64 rows)
    const int wc = wid & 1;         // 0..1  (N half, 64 cols)
    const int fr = lane & 15;
    const int fq = lane >> 4;

    // bijective XCD swizzle: 512 wgs, 64 consecutive per XCD
    const int orig = blockIdx.x;
    const int nid  = (orig & 7) * 64 + (orig >> 3);
    const int bm = (nid >> 3) * 256;    // 64 M-tiles
    const int bn = (nid & 7) * 128;     // 8  N-tiles

    // staging: chunk c = i*512 + tid -> row = i*128 + (tid>>2), slot16 = tid&3.
    // pre-swizzled source col: slot ^ ((row>>1)&3) = (tid&3)^((tid>>3)&3).
    const int rA    = tid >> 2;                              // 0..127
    const int colSw = ((tid & 3) ^ ((tid >> 3) & 3)) * 8;    // ushort col
    const size_t srcA0 = (size_t)(bm + rA) * KD + colSw;
    const size_t srcB0 = (size_t)(bn + rA) * KD + colSw;

    // read-side swizzled fragment bases (ushort offsets)
    const int slotSw = (fq ^ ((fr >> 1) & 3)) * 8;
    const int aOff = (wr * 64 + fr) * 32 + slotSw;
    const int bOff = (wc * 64 + fr) * 32 + slotSw;
    const ushort* Ab = &Lds[0];
    const ushort* Bb = &Lds[4 * 8192];

    f32x4 acc[4][4];
#pragma unroll
    for (int m = 0; m < 4; ++m)
#pragma unroll
        for (int n = 0; n < 4; ++n) acc[m][n] = (f32x4){0.f, 0.f, 0.f, 0.f};

    auto stage = [&](int slot, int ksub) {
        const ushort* Ap = A + srcA0 + ksub * 32;
        const ushort* Bp = Bt + srcB0 + ksub * 32;
#pragma unroll
        for (int i = 0; i < 2; ++i)
            __builtin_amdgcn_global_load_lds(
                (const __attribute__((address_space(1))) void*)(Ap + (size_t)i * 128 * KD),
                (__attribute__((address_space(3))) void*)(&Lds[slot * 8192 + i * 4096 + wid * 512]),
                16, 0, 0);
        __builtin_amdgcn_global_load_lds(
            (const __attribute__((address_space(1))) void*)Bp,
            (__attribute__((address_space(3))) void*)(&Lds[4 * 8192 + slot * 4096 + wid * 512]),
            16, 0, 0);
    };

    bf16x8 f0a[4], f0b[4], f1a[4], f1b[4];

    // prologue: stage ksubs 0,1,2 -> slots 0,1,2 (9 loads); drain slots 0,1
    stage(0, 0);
    stage(1, 1);
    stage(2, 2);
    VM3;                                  // drains 6 oldest: slots 0 and 1
    __builtin_amdgcn_sched_barrier(0);
    __builtin_amdgcn_s_barrier();
    __builtin_amdgcn_sched_barrier(0);
    READF(f0a, f0b, 0)                    // frags(0)
    asm volatile("s_waitcnt lgkmcnt(0)" ::: "memory");
    __builtin_amdgcn_sched_barrier(0);

    // main: phases p = 4j .. 4j+3, j = 0..6 (p = 0..27)
#pragma unroll 1
    for (int j = 0; j < 7; ++j) {
        const int k4 = 4 * j;
        OLPHASE(f0a, f0b, f1a, f1b, 1, true, 3, k4 + 3, VM3)   // p=4j
        OLPHASE(f1a, f1b, f0a, f0b, 2, true, 0, k4 + 4, VM3)   // p=4j+1
        OLPHASE(f0a, f0b, f1a, f1b, 3, true, 1, k4 + 5, VM3)   // p=4j+2
        OLPHASE(f1a, f1b, f0a, f0b, 0, true, 2, k4 + 6, VM3)   // p=4j+3
    }
    // tail: p=28..31
    OLPHASE(f0a, f0b, f1a, f1b, 1, true, 3, 31, VM3)           // p=28
    OLPHASE(f1a, f1b, f0a, f0b, 2, false, 0, 0, VM0)           // p=29
    {                                                          // p=30
        READF(f1a, f1b, 3)
        __builtin_amdgcn_sched_barrier(0);
        MFMAB(f0a, f0b)
        asm volatile("s_waitcnt lgkmcnt(0)" ::: "memory");
        __builtin_amdgcn_sched_barrier(0);
    }
    MFMAB(f1a, f1b)                                            // p=31

    // epilogue: C/D layout col=lane&15, row=(lane>>4)*4+r
#pragma unroll
    for (int n = 0; n < 4; ++n) {
        int col = bn + wc * 64 + n * 16 + fr;
        float bv = bias[col];
#pragma unroll
        for (int m = 0; m < 4; ++m) {
#pragma unroll
            for (int r = 0; r < 4; ++r) {
                int row = bm + wr * 64 + m * 16 + fq * 4 + r;
                float v = acc[m][n][r] + bv;
                if (OUT_BF16)
                    ((ushort*)Cp)[(size_t)row * ldc + col] = f2bf(v);
                else
                    ((float*)Cp)[(size_t)row * ldc + col] = v;
            }
        }
    }
}

// ---------------------------------------------------------------------------
// Skinny GEMM for q: BM=64, BN=128(pad of 112), BK=32, 256 thr.
// ---------------------------------------------------------------------------
__global__ __launch_bounds__(256) void gemm_small(const ushort* __restrict__ A,
                                                  const ushort* __restrict__ Bt,
                                                  const float* __restrict__ bias,
                                                  float* __restrict__ Cp) {
    __shared__ ushort Als[64 * 32];
    __shared__ ushort Bls[128 * 32];
    const int tid  = threadIdx.x;
    const int lane = tid & 63;
    const int wid  = tid >> 6;
    const int wr = wid >> 1, wc = wid & 1;
    const int bm = blockIdx.y * 64;
    const int fq = lane >> 4, fr = lane & 15;

    f32x4 acc[2][4];
#pragma unroll
    for (int m = 0; m < 2; ++m)
#pragma unroll
        for (int n = 0; n < 4; ++n) acc[m][n] = (f32x4){0.f, 0.f, 0.f, 0.f};

    const int rA = tid >> 2, oA = (tid & 3) * 8;
    for (int k0 = 0; k0 < KD; k0 += 32) {
        __builtin_amdgcn_global_load_lds(
            (const __attribute__((address_space(1))) void*)&A[(size_t)(bm + rA) * KD + k0 + oA],
            (__attribute__((address_space(3))) void*)&Als[wid * 64 * 8], 16, 0, 0);
#pragma unroll
        for (int i = 0; i < 2; ++i) {
            int c = i * 256 + tid;
            __builtin_amdgcn_global_load_lds(
                (const __attribute__((address_space(1))) void*)&Bt[(size_t)(c >> 2) * KD + k0 + (c & 3) * 8],
                (__attribute__((address_space(3))) void*)&Bls[(i * 256 + wid * 64) * 8], 16, 0, 0);
        }
        __syncthreads();

        bf16x8 af[2], bfr[4];
#pragma unroll
        for (int m = 0; m < 2; ++m)
            af[m] = *(const bf16x8*)&Als[(wr * 32 + m * 16 + fr) * 32 + fq * 8];
#pragma unroll
        for (int n = 0; n < 4; ++n)
            bfr[n] = *(const bf16x8*)&Bls[(wc * 64 + n * 16 + fr) * 32 + fq * 8];
#pragma unroll
        for (int m = 0; m < 2; ++m)
#pragma unroll
            for (int n = 0; n < 4; ++n)
                acc[m][n] = __builtin_amdgcn_mfma_f32_16x16x32_bf16(
                    af[m], bfr[n], acc[m][n], 0, 0, 0);
        __syncthreads();
    }

#pragma unroll
    for (int m = 0; m < 2; ++m) {
#pragma unroll
        for (int n = 0; n < 4; ++n) {
            int col = wc * 64 + n * 16 + fr;
            if (col >= HK) continue;
            float bv = bias[col];
#pragma unroll
            for (int r = 0; r < 4; ++r) {
                int row = bm + wr * 32 + m * 16 + fq * 4 + r;
                Cp[(size_t)row * HK + col] = acc[m][n][r] + bv;
            }
        }
    }
}

// ---------------------------------------------------------------------------
// Tiled dynamic conv + fused softmax: block = (b, 16 consecutive t).
// ---------------------------------------------------------------------------
__global__ __launch_bounds__(256) void dynconv2(const ushort* __restrict__ h,
                                                const float* __restrict__ q,
                                                const float* __restrict__ cbias,
                                                ushort* __restrict__ out) {
    __shared__ ushort hw[22][1024];
    __shared__ float wsm[16][HK];
    const int tid = threadIdx.x;
    const int b  = blockIdx.x & 15;
    const int t0 = (blockIdx.x >> 4) << 4;

    for (int i = tid; i < 22 * 128; i += 256) {
        int wrow = i >> 7;
        int c8   = (i & 127) * 8;
        int tt   = t0 + wrow - PAD_LEFT;
        uint4 v = make_uint4(0, 0, 0, 0);
        if (tt >= 0 && tt < T_DIM)
            v = *(const uint4*)&h[((size_t)tt * B_DIM + b) * C_DIM + c8];
        *(uint4*)&hw[wrow][c8] = v;
    }
    {
        int tl = tid >> 4, hh = tid & 15;
        int m = (t0 + tl) * B_DIM + b;
        const float* p = &q[(size_t)m * HK + hh * K_TAPS];
        float mx = p[0];
#pragma unroll
        for (int k = 1; k < K_TAPS; ++k) mx = fmaxf(mx, p[k]);
        float e[K_TAPS], s = 0.f;
#pragma unroll
        for (int k = 0; k < K_TAPS; ++k) { e[k] = __expf(p[k] - mx); s += e[k]; }
        float inv = 1.f / s;
#pragma unroll
        for (int k = 0; k < K_TAPS; ++k) wsm[tl][hh * K_TAPS + k] = e[k] * inv;
    }
    __syncthreads();

    const int c  = tid * 4;
    const int hh = c >> 6;
    float4 bias = *(const float4*)&cbias[c];

    for (int tl = 0; tl < 16; ++tl) {
        float a0 = bias.x, a1 = bias.y, a2 = bias.z, a3 = bias.w;
#pragma unroll
        for (int k = 0; k < K_TAPS; ++k) {
            ushort4 hv = *(const ushort4*)&hw[tl + k][c];
            float wk = wsm[tl][hh * K_TAPS + k];
            a0 = fmaf(bf2f(hv.x), wk, a0);
            a1 = fmaf(bf2f(hv.y), wk, a1);
            a2 = fmaf(bf2f(hv.z), wk, a2);
            a3 = fmaf(bf2f(hv.w), wk, a3);
        }
        ushort4 o;
        o.x = f2bf(a0); o.y = f2bf(a1); o.z = f2bf(a2); o.w = f2bf(a3);
        *(ushort4*)&out[((size_t)(t0 + tl) * B_DIM + b) * C_DIM + c] = o;
    }
}

// ---------------------------------------------------------------------------
extern "C" void kernel_launch(void* const* d_in, const int* in_sizes, int n_in,
                              void* d_out, int out_size, void* d_ws,
                              size_t ws_size, hipStream_t stream) {
    const float* x     = (const float*)d_in[0];
    const float* W1    = (const float*)d_in[1];
    const float* b1    = (const float*)d_in[2];
    const float* Wq    = (const float*)d_in[3];
    const float* bq    = (const float*)d_in[4];
    const float* cbias = (const float*)d_in[5];
    const float* W2    = (const float*)d_in[6];
    const float* b2    = (const float*)d_in[7];
    float* out = (float*)d_out;

    ushort* xb    = (ushort*)d_ws;
    ushort* hb    = xb    + (size_t)M_DIM * C_DIM;
    ushort* convb = hb    + (size_t)M_DIM * C_DIM;
    ushort* W1t   = convb + (size_t)M_DIM * C_DIM;
    ushort* W2t   = W1t   + (size_t)C_DIM * C_DIM;
    ushort* Wqt   = W2t   + (size_t)C_DIM * OUT_DIM;
    float*  q     = (float*)(Wqt + (size_t)HKP * C_DIM);

    // 0) prep: x -> bf16, weights -> transposed bf16 (one launch)
    prep<<<dim3(8192 + 68 * 32), dim3(256), 0, stream>>>(
        x, xb, W1, Wq, W2, W1t, Wqt, W2t);

    // 1) h = bf16(x @ W1 + b1)   [512 wgs, 512 thr, 1 block/CU]
    gemm_ol<true><<<dim3(512), dim3(512), 0, stream>>>(xb, W1t, b1, hb, C_DIM);

    // 2) q = h @ Wq + bq   [16384 x 112]
    gemm_small<<<dim3(1, M_DIM / 64), dim3(256), 0, stream>>>(hb, Wqt, bq, q);

    // 3+4) conv = bf16(dynconv(h, softmax(q)) + conv_bias)
    dynconv2<<<dim3(B_DIM * T_DIM / 16), dim3(256), 0, stream>>>(
        hb, q, cbias, convb);

    // 5) out = conv @ W2 + b2
    gemm_ol<false><<<dim3(512), dim3(512), 0, stream>>>(convb, W2t, b2, out,
                                                        OUT_DIM);
}

// Round 18
// 146.764 us; speedup vs baseline: 1.0341x; 1.0341x over previous
//
#include <hip/hip_runtime.h>
#include <math.h>

#define T_DIM 1024
#define B_DIM 16
#define C_DIM 1024
#define H_DIM 16
#define K_TAPS 7
#define PAD_LEFT 3
#define OUT_DIM 1024
#define M_DIM (T_DIM * B_DIM)   // 16384
#define HK 112
#define HKP 128
#define KD 1024

typedef __attribute__((ext_vector_type(8))) short bf16x8;
typedef __attribute__((ext_vector_type(4))) float f32x4;

__device__ __forceinline__ ushort f2bf(float f) {
    union { float f; unsigned u; } v; v.f = f;
    unsigned u = v.u;
    u += 0x7fffu + ((u >> 16) & 1u);
    return (ushort)(u >> 16);
}
__device__ __forceinline__ float bf2f(ushort h) {
    union { unsigned u; float f; } v; v.u = ((unsigned)h) << 16;
    return v.f;
}

// ---------------------------------------------------------------------------
// Fused prep: blocks 0-8191 convert x -> bf16; blocks 8192+ transpose weights.
// ---------------------------------------------------------------------------
__global__ __launch_bounds__(256) void prep(const float* __restrict__ x,
                                            ushort* __restrict__ xb,
                                            const float* __restrict__ W1s,
                                            const float* __restrict__ Wqs,
                                            const float* __restrict__ W2s,
                                            ushort* __restrict__ W1t,
                                            ushort* __restrict__ Wqt,
                                            ushort* __restrict__ W2t) {
    __shared__ float tile[32][33];
    const int bx = blockIdx.x;
    if (bx < 8192) {
        int i = bx * 256 + threadIdx.x;
        const float4* p = (const float4*)x;
        float4 a = p[2 * i], b = p[2 * i + 1];
        uint4 o;
        o.x = (unsigned)f2bf(a.x) | ((unsigned)f2bf(a.y) << 16);
        o.y = (unsigned)f2bf(a.z) | ((unsigned)f2bf(a.w) << 16);
        o.z = (unsigned)f2bf(b.x) | ((unsigned)f2bf(b.y) << 16);
        o.w = (unsigned)f2bf(b.z) | ((unsigned)f2bf(b.w) << 16);
        ((uint4*)xb)[i] = o;
        return;
    }
    int tb  = bx - 8192;
    int nbx = tb % 68;
    int k0  = (tb / 68) * 32;
    const float* W; ushort* Wt; int N, Npad, nb;
    if (nbx < 32)      { W = W1s; Wt = W1t; N = 1024; Npad = 1024; nb = nbx; }
    else if (nbx < 36) { W = Wqs; Wt = Wqt; N = 112;  Npad = 128;  nb = nbx - 32; }
    else               { W = W2s; Wt = W2t; N = 1024; Npad = 1024; nb = nbx - 36; }
    int n0 = nb * 32;
    int tx = threadIdx.x & 31, ty = threadIdx.x >> 5;
#pragma unroll
    for (int j = 0; j < 4; ++j) {
        int k = k0 + ty * 4 + j;
        int n = n0 + tx;
        tile[ty * 4 + j][tx] = (n < N) ? W[(size_t)k * N + n] : 0.f;
    }
    __syncthreads();
#pragma unroll
    for (int j = 0; j < 4; ++j) {
        int n = n0 + ty * 4 + j;
        if (n < Npad)
            Wt[(size_t)n * KD + k0 + tx] = f2bf(tile[tx][ty * 4 + j]);
    }
}

// ---------------------------------------------------------------------------
// 256x256 bf16 MFMA GEMM, 4 mega-phase schedule (R16 structure) with ONE
// barrier per phase (second barrier dropped — safety proof in R17 notes:
// stage(p) follows barrier1(p-1), by which every wave has executed its
// vmcnt(p-1) [slot staged at p-2 is landed CU-wide] and its lgkm0(p-2)
// [reads of the re-staged slot, last touched p-3, are drained]).
// Swizzle: 16B slot' = slot^((row>>1)&3), pre-swizzled source + swizzled read.
// vmcnt: steady 8; tail j=7: mp1=vmcnt(4), mp2=vmcnt(0).
// ---------------------------------------------------------------------------
#define MPHASE(SLOT, STAGE_STMT, VM_STMT)                                     \
    {                                                                         \
        bf16x8 b[4], a_[8];                                                   \
        _Pragma("unroll")                                                     \
        for (int n = 0; n < 4; ++n)                                           \
            b[n] = *(const bf16x8*)(Bbase + (SLOT)*8192 + bOff + n*512);      \
        _Pragma("unroll")                                                     \
        for (int m = 0; m < 8; ++m)                                           \
            a_[m] = *(const bf16x8*)(Abase + (SLOT)*8192 + aOff +             \
                                     (m >> 2)*2048 + (m & 3)*512);            \
        STAGE_STMT;                                                           \
        VM_STMT;                                                              \
        __builtin_amdgcn_s_barrier();                                         \
        asm volatile("s_waitcnt lgkmcnt(0)" ::: "memory");                    \
        __builtin_amdgcn_sched_barrier(0);                                    \
        __builtin_amdgcn_s_setprio(1);                                        \
        _Pragma("unroll")                                                     \
        for (int m = 0; m < 8; ++m)                                           \
            _Pragma("unroll")                                                 \
            for (int n = 0; n < 4; ++n)                                       \
                acc[m][n] = __builtin_amdgcn_mfma_f32_16x16x32_bf16(          \
                    a_[m], b[n], acc[m][n], 0, 0, 0);                         \
        __builtin_amdgcn_s_setprio(0);                                        \
        __builtin_amdgcn_sched_barrier(0);                                    \
    }

template <bool OUT_BF16>
__global__ __launch_bounds__(512, 1) void gemm8p(
    const ushort* __restrict__ A, const ushort* __restrict__ Bt,
    const float* __restrict__ bias, void* __restrict__ Cp, int ldc) {
    __shared__ ushort Lds[8 * 8192];   // A slots 0-3, B slots 4-7

    const int tid  = threadIdx.x;
    const int lane = tid & 63;
    const int wid  = tid >> 6;
    const int wr = wid >> 2;
    const int wc = wid & 3;
    const int fr = lane & 15;
    const int fq = lane >> 4;

    const int orig = blockIdx.x;
    const int nid  = (orig & 7) * 32 + (orig >> 3);
    const int bm = (nid >> 2) * 256;
    const int bn = (nid & 3) * 256;

    const int srow = tid >> 2;
    const int scol = ((tid & 3) ^ ((tid >> 3) & 3)) * 8;
    const size_t sA = (size_t)(bm + srow) * KD + scol;
    const size_t sB = (size_t)(bn + srow) * KD + scol;
    const int sdst = wid * 64 * 8;

    const int slotSw = (fq ^ ((fr >> 1) & 3)) * 8;
    const int aOff = (wr * 128 + fr) * 32 + slotSw;
    const int bOff = (wc * 64 + fr) * 32 + slotSw;
    const ushort* Abase = &Lds[0];
    const ushort* Bbase = &Lds[4 * 8192];

    f32x4 acc[8][4];
#pragma unroll
    for (int m = 0; m < 8; ++m)
#pragma unroll
        for (int n = 0; n < 4; ++n) acc[m][n] = (f32x4){0.f, 0.f, 0.f, 0.f};

    auto stageA = [&](int slot, int koff) {
#pragma unroll
        for (int i = 0; i < 2; ++i)
            __builtin_amdgcn_global_load_lds(
                (const __attribute__((address_space(1))) void*)(A + sA + koff + (size_t)i * 128 * KD),
                (__attribute__((address_space(3))) void*)(&Lds[slot * 8192 + i * 4096 + sdst]),
                16, 0, 0);
    };
    auto stageB = [&](int slot, int koff) {
#pragma unroll
        for (int i = 0; i < 2; ++i)
            __builtin_amdgcn_global_load_lds(
                (const __attribute__((address_space(1))) void*)(Bt + sB + koff + (size_t)i * 128 * KD),
                (__attribute__((address_space(3))) void*)(&Lds[(4 + slot) * 8192 + i * 4096 + sdst]),
                16, 0, 0);
    };

    stageA(0, 0);   stageB(0, 0);
    stageA(1, 32);  stageB(1, 32);
    stageA(2, 64);  stageB(2, 64);
    stageA(3, 96);  stageB(3, 96);
    asm volatile("s_waitcnt vmcnt(12)" ::: "memory");
    __builtin_amdgcn_sched_barrier(0);
    __builtin_amdgcn_s_barrier();
    __builtin_amdgcn_sched_barrier(0);

#pragma unroll 1
    for (int j = 0; j < 8; ++j) {
        const int e = 2 * j;

        // mp0: tile e, ksub0 | stage slot3 pair (tile e+1, k1) | vmcnt(8)
        MPHASE(0,
               { if (j >= 1) { stageA(3, (e + 1) * 64 + 32);
                               stageB(3, (e + 1) * 64 + 32); } },
               { asm volatile("s_waitcnt vmcnt(8)" ::: "memory");
                 __builtin_amdgcn_sched_barrier(0); })
        // mp1: tile e, ksub1 | stage slot0 pair (tile e+2, k0) | vmcnt(8)/(4)
        MPHASE(1,
               { if (j < 7) { stageA(0, (e + 2) * 64);
                              stageB(0, (e + 2) * 64); } },
               { if (j == 7) { asm volatile("s_waitcnt vmcnt(4)" ::: "memory"); }
                 else        { asm volatile("s_waitcnt vmcnt(8)" ::: "memory"); }
                 __builtin_amdgcn_sched_barrier(0); })
        // mp2: tile e+1, ksub0 | stage slot1 pair (tile e+2, k1) | vmcnt(8)/(0)
        MPHASE(2,
               { if (j < 7) { stageA(1, (e + 2) * 64 + 32);
                              stageB(1, (e + 2) * 64 + 32); } },
               { if (j == 7) { asm volatile("s_waitcnt vmcnt(0)" ::: "memory"); }
                 else        { asm volatile("s_waitcnt vmcnt(8)" ::: "memory"); }
                 __builtin_amdgcn_sched_barrier(0); })
        // mp3: tile e+1, ksub1 | stage slot2 pair (tile e+3, k0) | vmcnt(8)
        MPHASE(3,
               { if (j < 7) { stageA(2, (e + 3) * 64);
                              stageB(2, (e + 3) * 64); } },
               { if (j < 7) { asm volatile("s_waitcnt vmcnt(8)" ::: "memory");
                              __builtin_amdgcn_sched_barrier(0); } })
    }

    // epilogue: C/D layout col=lane&15, row=(lane>>4)*4+r
#pragma unroll
    for (int n = 0; n < 4; ++n) {
        int col = bn + wc * 64 + n * 16 + fr;
        float bv = bias[col];
#pragma unroll
        for (int m = 0; m < 8; ++m) {
#pragma unroll
            for (int r = 0; r < 4; ++r) {
                int row = bm + wr * 128 + m * 16 + fq * 4 + r;
                float v = acc[m][n][r] + bv;
                if (OUT_BF16)
                    ((ushort*)Cp)[(size_t)row * ldc + col] = f2bf(v);
                else
                    ((float*)Cp)[(size_t)row * ldc + col] = v;
            }
        }
    }
}

// ---------------------------------------------------------------------------
// Skinny GEMM for q: BM=64, BN=128(pad of 112), BK=32, 256 thr.
// ---------------------------------------------------------------------------
__global__ __launch_bounds__(256) void gemm_small(const ushort* __restrict__ A,
                                                  const ushort* __restrict__ Bt,
                                                  const float* __restrict__ bias,
                                                  float* __restrict__ Cp) {
    __shared__ ushort Als[64 * 32];
    __shared__ ushort Bls[128 * 32];
    const int tid  = threadIdx.x;
    const int lane = tid & 63;
    const int wid  = tid >> 6;
    const int wr = wid >> 1, wc = wid & 1;
    const int bm = blockIdx.y * 64;
    const int fq = lane >> 4, fr = lane & 15;

    f32x4 acc[2][4];
#pragma unroll
    for (int m = 0; m < 2; ++m)
#pragma unroll
        for (int n = 0; n < 4; ++n) acc[m][n] = (f32x4){0.f, 0.f, 0.f, 0.f};

    const int rA = tid >> 2, oA = (tid & 3) * 8;
    for (int k0 = 0; k0 < KD; k0 += 32) {
        __builtin_amdgcn_global_load_lds(
            (const __attribute__((address_space(1))) void*)&A[(size_t)(bm + rA) * KD + k0 + oA],
            (__attribute__((address_space(3))) void*)&Als[wid * 64 * 8], 16, 0, 0);
#pragma unroll
        for (int i = 0; i < 2; ++i) {
            int c = i * 256 + tid;
            __builtin_amdgcn_global_load_lds(
                (const __attribute__((address_space(1))) void*)&Bt[(size_t)(c >> 2) * KD + k0 + (c & 3) * 8],
                (__attribute__((address_space(3))) void*)&Bls[(i * 256 + wid * 64) * 8], 16, 0, 0);
        }
        __syncthreads();

        bf16x8 af[2], bfr[4];
#pragma unroll
        for (int m = 0; m < 2; ++m)
            af[m] = *(const bf16x8*)&Als[(wr * 32 + m * 16 + fr) * 32 + fq * 8];
#pragma unroll
        for (int n = 0; n < 4; ++n)
            bfr[n] = *(const bf16x8*)&Bls[(wc * 64 + n * 16 + fr) * 32 + fq * 8];
#pragma unroll
        for (int m = 0; m < 2; ++m)
#pragma unroll
            for (int n = 0; n < 4; ++n)
                acc[m][n] = __builtin_amdgcn_mfma_f32_16x16x32_bf16(
                    af[m], bfr[n], acc[m][n], 0, 0, 0);
        __syncthreads();
    }

#pragma unroll
    for (int m = 0; m < 2; ++m) {
#pragma unroll
        for (int n = 0; n < 4; ++n) {
            int col = wc * 64 + n * 16 + fr;
            if (col >= HK) continue;
            float bv = bias[col];
#pragma unroll
            for (int r = 0; r < 4; ++r) {
                int row = bm + wr * 32 + m * 16 + fq * 4 + r;
                Cp[(size_t)row * HK + col] = acc[m][n][r] + bv;
            }
        }
    }
}

// ---------------------------------------------------------------------------
// Tiled dynamic conv + fused softmax: block = (b, 16 consecutive t).
// ---------------------------------------------------------------------------
__global__ __launch_bounds__(256) void dynconv2(const ushort* __restrict__ h,
                                                const float* __restrict__ q,
                                                const float* __restrict__ cbias,
                                                ushort* __restrict__ out) {
    __shared__ ushort hw[22][1024];
    __shared__ float wsm[16][HK];
    const int tid = threadIdx.x;
    const int b  = blockIdx.x & 15;
    const int t0 = (blockIdx.x >> 4) << 4;

    for (int i = tid; i < 22 * 128; i += 256) {
        int wrow = i >> 7;
        int c8   = (i & 127) * 8;
        int tt   = t0 + wrow - PAD_LEFT;
        uint4 v = make_uint4(0, 0, 0, 0);
        if (tt >= 0 && tt < T_DIM)
            v = *(const uint4*)&h[((size_t)tt * B_DIM + b) * C_DIM + c8];
        *(uint4*)&hw[wrow][c8] = v;
    }
    {
        int tl = tid >> 4, hh = tid & 15;
        int m = (t0 + tl) * B_DIM + b;
        const float* p = &q[(size_t)m * HK + hh * K_TAPS];
        float mx = p[0];
#pragma unroll
        for (int k = 1; k < K_TAPS; ++k) mx = fmaxf(mx, p[k]);
        float e[K_TAPS], s = 0.f;
#pragma unroll
        for (int k = 0; k < K_TAPS; ++k) { e[k] = __expf(p[k] - mx); s += e[k]; }
        float inv = 1.f / s;
#pragma unroll
        for (int k = 0; k < K_TAPS; ++k) wsm[tl][hh * K_TAPS + k] = e[k] * inv;
    }
    __syncthreads();

    const int c  = tid * 4;
    const int hh = c >> 6;
    float4 bias = *(const float4*)&cbias[c];

    for (int tl = 0; tl < 16; ++tl) {
        float a0 = bias.x, a1 = bias.y, a2 = bias.z, a3 = bias.w;
#pragma unroll
        for (int k = 0; k < K_TAPS; ++k) {
            ushort4 hv = *(const ushort4*)&hw[tl + k][c];
            float wk = wsm[tl][hh * K_TAPS + k];
            a0 = fmaf(bf2f(hv.x), wk, a0);
            a1 = fmaf(bf2f(hv.y), wk, a1);
            a2 = fmaf(bf2f(hv.z), wk, a2);
            a3 = fmaf(bf2f(hv.w), wk, a3);
        }
        ushort4 o;
        o.x = f2bf(a0); o.y = f2bf(a1); o.z = f2bf(a2); o.w = f2bf(a3);
        *(ushort4*)&out[((size_t)(t0 + tl) * B_DIM + b) * C_DIM + c] = o;
    }
}

// ---------------------------------------------------------------------------
extern "C" void kernel_launch(void* const* d_in, const int* in_sizes, int n_in,
                              void* d_out, int out_size, void* d_ws,
                              size_t ws_size, hipStream_t stream) {
    const float* x     = (const float*)d_in[0];
    const float* W1    = (const float*)d_in[1];
    const float* b1    = (const float*)d_in[2];
    const float* Wq    = (const float*)d_in[3];
    const float* bq    = (const float*)d_in[4];
    const float* cbias = (const float*)d_in[5];
    const float* W2    = (const float*)d_in[6];
    const float* b2    = (const float*)d_in[7];
    float* out = (float*)d_out;

    ushort* xb    = (ushort*)d_ws;
    ushort* hb    = xb    + (size_t)M_DIM * C_DIM;
    ushort* convb = hb    + (size_t)M_DIM * C_DIM;
    ushort* W1t   = convb + (size_t)M_DIM * C_DIM;
    ushort* W2t   = W1t   + (size_t)C_DIM * C_DIM;
    ushort* Wqt   = W2t   + (size_t)C_DIM * OUT_DIM;
    float*  q     = (float*)(Wqt + (size_t)HKP * C_DIM);

    // 0) prep: x -> bf16, weights -> transposed bf16 (one launch)
    prep<<<dim3(8192 + 68 * 32), dim3(256), 0, stream>>>(
        x, xb, W1, Wq, W2, W1t, Wqt, W2t);

    // 1) h = bf16(x @ W1 + b1)
    gemm8p<true><<<dim3(256), dim3(512), 0, stream>>>(xb, W1t, b1, hb, C_DIM);

    // 2) q = h @ Wq + bq   [16384 x 112]
    gemm_small<<<dim3(1, M_DIM / 64), dim3(256), 0, stream>>>(hb, Wqt, bq, q);

    // 3+4) conv = bf16(dynconv(h, softmax(q)) + conv_bias)
    dynconv2<<<dim3(B_DIM * T_DIM / 16), dim3(256), 0, stream>>>(
        hb, q, cbias, convb);

    // 5) out = conv @ W2 + b2
    gemm8p<false><<<dim3(256), dim3(512), 0, stream>>>(convb, W2t, b2, out,
                                                       OUT_DIM);
}

// Round 19
// 146.396 us; speedup vs baseline: 1.0367x; 1.0025x over previous
//
#include <hip/hip_runtime.h>
#include <math.h>

#define T_DIM 1024
#define B_DIM 16
#define C_DIM 1024
#define H_DIM 16
#define K_TAPS 7
#define PAD_LEFT 3
#define OUT_DIM 1024
#define M_DIM (T_DIM * B_DIM)   // 16384
#define HK 112
#define HKP 128
#define KD 1024

typedef __attribute__((ext_vector_type(8))) short bf16x8;
typedef __attribute__((ext_vector_type(4))) float f32x4;
typedef __attribute__((ext_vector_type(16))) float f32x16;

__device__ __forceinline__ ushort f2bf(float f) {
    union { float f; unsigned u; } v; v.f = f;
    unsigned u = v.u;
    u += 0x7fffu + ((u >> 16) & 1u);
    return (ushort)(u >> 16);
}
__device__ __forceinline__ float bf2f(ushort h) {
    union { unsigned u; float f; } v; v.u = ((unsigned)h) << 16;
    return v.f;
}

// ---------------------------------------------------------------------------
// Fused prep: blocks 0-8191 convert x -> bf16; blocks 8192+ transpose weights.
// ---------------------------------------------------------------------------
__global__ __launch_bounds__(256) void prep(const float* __restrict__ x,
                                            ushort* __restrict__ xb,
                                            const float* __restrict__ W1s,
                                            const float* __restrict__ Wqs,
                                            const float* __restrict__ W2s,
                                            ushort* __restrict__ W1t,
                                            ushort* __restrict__ Wqt,
                                            ushort* __restrict__ W2t) {
    __shared__ float tile[32][33];
    const int bx = blockIdx.x;
    if (bx < 8192) {
        int i = bx * 256 + threadIdx.x;
        const float4* p = (const float4*)x;
        float4 a = p[2 * i], b = p[2 * i + 1];
        uint4 o;
        o.x = (unsigned)f2bf(a.x) | ((unsigned)f2bf(a.y) << 16);
        o.y = (unsigned)f2bf(a.z) | ((unsigned)f2bf(a.w) << 16);
        o.z = (unsigned)f2bf(b.x) | ((unsigned)f2bf(b.y) << 16);
        o.w = (unsigned)f2bf(b.z) | ((unsigned)f2bf(b.w) << 16);
        ((uint4*)xb)[i] = o;
        return;
    }
    int tb  = bx - 8192;
    int nbx = tb % 68;
    int k0  = (tb / 68) * 32;
    const float* W; ushort* Wt; int N, Npad, nb;
    if (nbx < 32)      { W = W1s; Wt = W1t; N = 1024; Npad = 1024; nb = nbx; }
    else if (nbx < 36) { W = Wqs; Wt = Wqt; N = 112;  Npad = 128;  nb = nbx - 32; }
    else               { W = W2s; Wt = W2t; N = 1024; Npad = 1024; nb = nbx - 36; }
    int n0 = nb * 32;
    int tx = threadIdx.x & 31, ty = threadIdx.x >> 5;
#pragma unroll
    for (int j = 0; j < 4; ++j) {
        int k = k0 + ty * 4 + j;
        int n = n0 + tx;
        tile[ty * 4 + j][tx] = (n < N) ? W[(size_t)k * N + n] : 0.f;
    }
    __syncthreads();
#pragma unroll
    for (int j = 0; j < 4; ++j) {
        int n = n0 + ty * 4 + j;
        if (n < Npad)
            Wt[(size_t)n * KD + k0 + tx] = f2bf(tile[tx][ty * 4 + j]);
    }
}

// ---------------------------------------------------------------------------
// 256x256 bf16 MFMA GEMM — R18 mega-phase skeleton (one barrier/phase,
// identical staging/slots/swizzle/vmcnt ledger) with the MFMA shape switched
// to 32x32x16 (2382 vs 2075 TF ceiling, halved instruction count, same LDS
// traffic: 12 ds_read_b128 + 4 gload_lds per phase).
// Fragment addressing: A-frag row = wr*128+mt*32+(lane&31), 16B slot =
// (kc*2+(lane>>5)) ^ (((lane&31)>>1)&3)  [wave-row terms ≡0 mod 4 -> lane-only
// mask; bank coverage per 8-lane group verified complete].
// C/D layout (m74/m101): col=lane&31, row=(reg&3)+8*(reg>>2)+4*(lane>>5).
// ---------------------------------------------------------------------------
#define MPHASE(SLOT, STAGE_STMT, VM_STMT)                                     \
    {                                                                         \
        bf16x8 a_[4][2], b_[2][2];                                            \
        _Pragma("unroll")                                                     \
        for (int mt = 0; mt < 4; ++mt)                                        \
            _Pragma("unroll")                                                 \
            for (int kc = 0; kc < 2; ++kc)                                    \
                a_[mt][kc] = *(const bf16x8*)(Abase + (SLOT)*8192 + aBase +   \
                                              mt*1024 + xk[kc]);              \
        _Pragma("unroll")                                                     \
        for (int nt = 0; nt < 2; ++nt)                                        \
            _Pragma("unroll")                                                 \
            for (int kc = 0; kc < 2; ++kc)                                    \
                b_[nt][kc] = *(const bf16x8*)(Bbase + (SLOT)*8192 + bBase +   \
                                              nt*1024 + xk[kc]);              \
        STAGE_STMT;                                                           \
        VM_STMT;                                                              \
        __builtin_amdgcn_s_barrier();                                         \
        asm volatile("s_waitcnt lgkmcnt(0)" ::: "memory");                    \
        __builtin_amdgcn_sched_barrier(0);                                    \
        __builtin_amdgcn_s_setprio(1);                                        \
        _Pragma("unroll")                                                     \
        for (int mt = 0; mt < 4; ++mt)                                        \
            _Pragma("unroll")                                                 \
            for (int nt = 0; nt < 2; ++nt)                                    \
                _Pragma("unroll")                                             \
                for (int kc = 0; kc < 2; ++kc)                                \
                    acc[mt*2 + nt] = __builtin_amdgcn_mfma_f32_32x32x16_bf16( \
                        a_[mt][kc], b_[nt][kc], acc[mt*2 + nt], 0, 0, 0);     \
        __builtin_amdgcn_s_setprio(0);                                        \
        __builtin_amdgcn_sched_barrier(0);                                    \
    }

template <bool OUT_BF16>
__global__ __launch_bounds__(512, 1) void gemm32(
    const ushort* __restrict__ A, const ushort* __restrict__ Bt,
    const float* __restrict__ bias, void* __restrict__ Cp, int ldc) {
    __shared__ ushort Lds[8 * 8192];   // A slots 0-3, B slots 4-7

    const int tid  = threadIdx.x;
    const int lane = tid & 63;
    const int wid  = tid >> 6;
    const int wr = wid >> 2;        // 0..1  (M half, 128 rows)
    const int wc = wid & 3;         // 0..3  (N quarter, 64 cols)
    const int l5 = lane & 31;       // row within 32-tile
    const int hi = lane >> 5;       // k-half selector

    const int orig = blockIdx.x;
    const int nid  = (orig & 7) * 32 + (orig >> 3);
    const int bm = (nid >> 2) * 256;
    const int bn = (nid & 3) * 256;

    // staging (identical to R18): linear LDS dest, pre-swizzled global col
    const int srow = tid >> 2;
    const int scol = ((tid & 3) ^ ((tid >> 3) & 3)) * 8;
    const size_t sA = (size_t)(bm + srow) * KD + scol;
    const size_t sB = (size_t)(bn + srow) * KD + scol;
    const int sdst = wid * 64 * 8;

    // read-side: 16B slot (kc*2+hi) ^ lmask, lmask = ((lane&31)>>1)&3
    const int lmask = (l5 >> 1) & 3;
    int xk[2];
#pragma unroll
    for (int kc = 0; kc < 2; ++kc) xk[kc] = ((kc * 2 + hi) ^ lmask) * 8;
    const int aBase = (wr * 128 + l5) * 32;
    const int bBase = (wc * 64 + l5) * 32;
    const ushort* Abase = &Lds[0];
    const ushort* Bbase = &Lds[4 * 8192];

    f32x16 acc[8];
#pragma unroll
    for (int t = 0; t < 8; ++t)
#pragma unroll
        for (int r = 0; r < 16; ++r) acc[t][r] = 0.f;

    auto stageA = [&](int slot, int koff) {
#pragma unroll
        for (int i = 0; i < 2; ++i)
            __builtin_amdgcn_global_load_lds(
                (const __attribute__((address_space(1))) void*)(A + sA + koff + (size_t)i * 128 * KD),
                (__attribute__((address_space(3))) void*)(&Lds[slot * 8192 + i * 4096 + sdst]),
                16, 0, 0);
    };
    auto stageB = [&](int slot, int koff) {
#pragma unroll
        for (int i = 0; i < 2; ++i)
            __builtin_amdgcn_global_load_lds(
                (const __attribute__((address_space(1))) void*)(Bt + sB + koff + (size_t)i * 128 * KD),
                (__attribute__((address_space(3))) void*)(&Lds[(4 + slot) * 8192 + i * 4096 + sdst]),
                16, 0, 0);
    };

    stageA(0, 0);   stageB(0, 0);
    stageA(1, 32);  stageB(1, 32);
    stageA(2, 64);  stageB(2, 64);
    stageA(3, 96);  stageB(3, 96);
    asm volatile("s_waitcnt vmcnt(12)" ::: "memory");
    __builtin_amdgcn_sched_barrier(0);
    __builtin_amdgcn_s_barrier();
    __builtin_amdgcn_sched_barrier(0);

#pragma unroll 1
    for (int j = 0; j < 8; ++j) {
        const int e = 2 * j;

        // mp0: tile e, ksub0 | stage slot3 pair (tile e+1, k1) | vmcnt(8)
        MPHASE(0,
               { if (j >= 1) { stageA(3, (e + 1) * 64 + 32);
                               stageB(3, (e + 1) * 64 + 32); } },
               { asm volatile("s_waitcnt vmcnt(8)" ::: "memory");
                 __builtin_amdgcn_sched_barrier(0); })
        // mp1: tile e, ksub1 | stage slot0 pair (tile e+2, k0) | vmcnt(8)/(4)
        MPHASE(1,
               { if (j < 7) { stageA(0, (e + 2) * 64);
                              stageB(0, (e + 2) * 64); } },
               { if (j == 7) { asm volatile("s_waitcnt vmcnt(4)" ::: "memory"); }
                 else        { asm volatile("s_waitcnt vmcnt(8)" ::: "memory"); }
                 __builtin_amdgcn_sched_barrier(0); })
        // mp2: tile e+1, ksub0 | stage slot1 pair (tile e+2, k1) | vmcnt(8)/(0)
        MPHASE(2,
               { if (j < 7) { stageA(1, (e + 2) * 64 + 32);
                              stageB(1, (e + 2) * 64 + 32); } },
               { if (j == 7) { asm volatile("s_waitcnt vmcnt(0)" ::: "memory"); }
                 else        { asm volatile("s_waitcnt vmcnt(8)" ::: "memory"); }
                 __builtin_amdgcn_sched_barrier(0); })
        // mp3: tile e+1, ksub1 | stage slot2 pair (tile e+3, k0) | vmcnt(8)
        MPHASE(3,
               { if (j < 7) { stageA(2, (e + 3) * 64);
                              stageB(2, (e + 3) * 64); } },
               { if (j < 7) { asm volatile("s_waitcnt vmcnt(8)" ::: "memory");
                              __builtin_amdgcn_sched_barrier(0); } })
    }

    // epilogue: 32x32 C/D layout col=lane&31, row=(r&3)+8*(r>>2)+4*hi
#pragma unroll
    for (int mt = 0; mt < 4; ++mt) {
#pragma unroll
        for (int nt = 0; nt < 2; ++nt) {
            int col = bn + wc * 64 + nt * 32 + l5;
            float bv = bias[col];
#pragma unroll
            for (int r = 0; r < 16; ++r) {
                int row = bm + wr * 128 + mt * 32 + (r & 3) + 8 * (r >> 2) + 4 * hi;
                float v = acc[mt * 2 + nt][r] + bv;
                if (OUT_BF16)
                    ((ushort*)Cp)[(size_t)row * ldc + col] = f2bf(v);
                else
                    ((float*)Cp)[(size_t)row * ldc + col] = v;
            }
        }
    }
}

// ---------------------------------------------------------------------------
// Skinny GEMM for q: BM=64, BN=128(pad of 112), BK=32, 256 thr.
// ---------------------------------------------------------------------------
__global__ __launch_bounds__(256) void gemm_small(const ushort* __restrict__ A,
                                                  const ushort* __restrict__ Bt,
                                                  const float* __restrict__ bias,
                                                  float* __restrict__ Cp) {
    __shared__ ushort Als[64 * 32];
    __shared__ ushort Bls[128 * 32];
    const int tid  = threadIdx.x;
    const int lane = tid & 63;
    const int wid  = tid >> 6;
    const int wr = wid >> 1, wc = wid & 1;
    const int bm = blockIdx.y * 64;
    const int fq = lane >> 4, fr = lane & 15;

    f32x4 acc[2][4];
#pragma unroll
    for (int m = 0; m < 2; ++m)
#pragma unroll
        for (int n = 0; n < 4; ++n) acc[m][n] = (f32x4){0.f, 0.f, 0.f, 0.f};

    const int rA = tid >> 2, oA = (tid & 3) * 8;
    for (int k0 = 0; k0 < KD; k0 += 32) {
        __builtin_amdgcn_global_load_lds(
            (const __attribute__((address_space(1))) void*)&A[(size_t)(bm + rA) * KD + k0 + oA],
            (__attribute__((address_space(3))) void*)&Als[wid * 64 * 8], 16, 0, 0);
#pragma unroll
        for (int i = 0; i < 2; ++i) {
            int c = i * 256 + tid;
            __builtin_amdgcn_global_load_lds(
                (const __attribute__((address_space(1))) void*)&Bt[(size_t)(c >> 2) * KD + k0 + (c & 3) * 8],
                (__attribute__((address_space(3))) void*)&Bls[(i * 256 + wid * 64) * 8], 16, 0, 0);
        }
        __syncthreads();

        bf16x8 af[2], bfr[4];
#pragma unroll
        for (int m = 0; m < 2; ++m)
            af[m] = *(const bf16x8*)&Als[(wr * 32 + m * 16 + fr) * 32 + fq * 8];
#pragma unroll
        for (int n = 0; n < 4; ++n)
            bfr[n] = *(const bf16x8*)&Bls[(wc * 64 + n * 16 + fr) * 32 + fq * 8];
#pragma unroll
        for (int m = 0; m < 2; ++m)
#pragma unroll
            for (int n = 0; n < 4; ++n)
                acc[m][n] = __builtin_amdgcn_mfma_f32_16x16x32_bf16(
                    af[m], bfr[n], acc[m][n], 0, 0, 0);
        __syncthreads();
    }

#pragma unroll
    for (int m = 0; m < 2; ++m) {
#pragma unroll
        for (int n = 0; n < 4; ++n) {
            int col = wc * 64 + n * 16 + fr;
            if (col >= HK) continue;
            float bv = bias[col];
#pragma unroll
            for (int r = 0; r < 4; ++r) {
                int row = bm + wr * 32 + m * 16 + fq * 4 + r;
                Cp[(size_t)row * HK + col] = acc[m][n][r] + bv;
            }
        }
    }
}

// ---------------------------------------------------------------------------
// Tiled dynamic conv + fused softmax: block = (b, 16 consecutive t).
// ---------------------------------------------------------------------------
__global__ __launch_bounds__(256) void dynconv2(const ushort* __restrict__ h,
                                                const float* __restrict__ q,
                                                const float* __restrict__ cbias,
                                                ushort* __restrict__ out) {
    __shared__ ushort hw[22][1024];
    __shared__ float wsm[16][HK];
    const int tid = threadIdx.x;
    const int b  = blockIdx.x & 15;
    const int t0 = (blockIdx.x >> 4) << 4;

    for (int i = tid; i < 22 * 128; i += 256) {
        int wrow = i >> 7;
        int c8   = (i & 127) * 8;
        int tt   = t0 + wrow - PAD_LEFT;
        uint4 v = make_uint4(0, 0, 0, 0);
        if (tt >= 0 && tt < T_DIM)
            v = *(const uint4*)&h[((size_t)tt * B_DIM + b) * C_DIM + c8];
        *(uint4*)&hw[wrow][c8] = v;
    }
    {
        int tl = tid >> 4, hh = tid & 15;
        int m = (t0 + tl) * B_DIM + b;
        const float* p = &q[(size_t)m * HK + hh * K_TAPS];
        float mx = p[0];
#pragma unroll
        for (int k = 1; k < K_TAPS; ++k) mx = fmaxf(mx, p[k]);
        float e[K_TAPS], s = 0.f;
#pragma unroll
        for (int k = 0; k < K_TAPS; ++k) { e[k] = __expf(p[k] - mx); s += e[k]; }
        float inv = 1.f / s;
#pragma unroll
        for (int k = 0; k < K_TAPS; ++k) wsm[tl][hh * K_TAPS + k] = e[k] * inv;
    }
    __syncthreads();

    const int c  = tid * 4;
    const int hh = c >> 6;
    float4 bias = *(const float4*)&cbias[c];

    for (int tl = 0; tl < 16; ++tl) {
        float a0 = bias.x, a1 = bias.y, a2 = bias.z, a3 = bias.w;
#pragma unroll
        for (int k = 0; k < K_TAPS; ++k) {
            ushort4 hv = *(const ushort4*)&hw[tl + k][c];
            float wk = wsm[tl][hh * K_TAPS + k];
            a0 = fmaf(bf2f(hv.x), wk, a0);
            a1 = fmaf(bf2f(hv.y), wk, a1);
            a2 = fmaf(bf2f(hv.z), wk, a2);
            a3 = fmaf(bf2f(hv.w), wk, a3);
        }
        ushort4 o;
        o.x = f2bf(a0); o.y = f2bf(a1); o.z = f2bf(a2); o.w = f2bf(a3);
        *(ushort4*)&out[((size_t)(t0 + tl) * B_DIM + b) * C_DIM + c] = o;
    }
}

// ---------------------------------------------------------------------------
extern "C" void kernel_launch(void* const* d_in, const int* in_sizes, int n_in,
                              void* d_out, int out_size, void* d_ws,
                              size_t ws_size, hipStream_t stream) {
    const float* x     = (const float*)d_in[0];
    const float* W1    = (const float*)d_in[1];
    const float* b1    = (const float*)d_in[2];
    const float* Wq    = (const float*)d_in[3];
    const float* bq    = (const float*)d_in[4];
    const float* cbias = (const float*)d_in[5];
    const float* W2    = (const float*)d_in[6];
    const float* b2    = (const float*)d_in[7];
    float* out = (float*)d_out;

    ushort* xb    = (ushort*)d_ws;
    ushort* hb    = xb    + (size_t)M_DIM * C_DIM;
    ushort* convb = hb    + (size_t)M_DIM * C_DIM;
    ushort* W1t   = convb + (size_t)M_DIM * C_DIM;
    ushort* W2t   = W1t   + (size_t)C_DIM * C_DIM;
    ushort* Wqt   = W2t   + (size_t)C_DIM * OUT_DIM;
    float*  q     = (float*)(Wqt + (size_t)HKP * C_DIM);

    // 0) prep: x -> bf16, weights -> transposed bf16 (one launch)
    prep<<<dim3(8192 + 68 * 32), dim3(256), 0, stream>>>(
        x, xb, W1, Wq, W2, W1t, Wqt, W2t);

    // 1) h = bf16(x @ W1 + b1)
    gemm32<true><<<dim3(256), dim3(512), 0, stream>>>(xb, W1t, b1, hb, C_DIM);

    // 2) q = h @ Wq + bq   [16384 x 112]
    gemm_small<<<dim3(1, M_DIM / 64), dim3(256), 0, stream>>>(hb, Wqt, bq, q);

    // 3+4) conv = bf16(dynconv(h, softmax(q)) + conv_bias)
    dynconv2<<<dim3(B_DIM * T_DIM / 16), dim3(256), 0, stream>>>(
        hb, q, cbias, convb);

    // 5) out = conv @ W2 + b2
    gemm32<false><<<dim3(256), dim3(512), 0, stream>>>(convb, W2t, b2, out,
                                                       OUT_DIM);
}